// Round 20
// baseline (257.834 us; speedup 1.0000x reference)
//
#include <hip/hip_runtime.h>

typedef _Float16 half2_t __attribute__((ext_vector_type(2)));
typedef _Float16 half4_t __attribute__((ext_vector_type(4)));
typedef _Float16 half8_t __attribute__((ext_vector_type(8)));
typedef __attribute__((ext_vector_type(4))) float f32x4;

#define NV 100000
#define NTILE 6250      // 16 vertices per tile
#define GRID 512        // 2 blocks/CU, persistent grid-stride (= capacity)
#define LDSZ 81920      // 64K X dbuf + 8K xud/qB dbuf + 8K lin quad

#define VMWAIT(N) asm volatile("s_waitcnt vmcnt(" #N ")" ::: "memory")
#define LGKM0     asm volatile("s_waitcnt lgkmcnt(0)" ::: "memory")
#define FENCE     asm volatile("" ::: "memory")

__device__ __forceinline__ unsigned cvt_pk_u(float a, float b) {
  auto h = __builtin_amdgcn_cvt_pkrtz(a, b);
  return __builtin_bit_cast(unsigned, h);
}
__device__ __forceinline__ half2_t u2h(unsigned u) { return __builtin_bit_cast(half2_t, u); }
// generic -> 32-bit LDS offset (for inline-asm ds ops)
__device__ __forceinline__ unsigned lds_off(const void* p) {
  return (unsigned)(size_t)(const __attribute__((address_space(3))) char*)p;
}
// async global->LDS: lds dest = wave-uniform base + lane*16 (HW rule)
__device__ __forceinline__ void load16_to_lds(const void* g, void* s) {
  __builtin_amdgcn_global_load_lds(
      (const __attribute__((address_space(1))) unsigned int*)g,
      (__attribute__((address_space(3))) unsigned int*)s, 16, 0, 0);
}

// PREPASS: per-edge in-lane softmax over m; q -> swizzled Q_B overlay on the
// xud records of slot XUDs (wave-private region).  (verbatim R12 math)
#define PREPASS(XUDs, LINs, XS)                                               \
  {                                                                           \
    uint4 xd4 = *(const uint4*)((XUDs) + (wave * 64 + l) * 16);               \
    float evv = ((const float*)((LINs) + 1024))[wave * 64 + l];               \
    half2_t xm01 = u2h((XS).x), xm23 = u2h((XS).y);                           \
    half2_t xm45 = u2h((XS).z), xm67 = u2h((XS).w);                           \
    half2_t xd01 = u2h(xd4.x), xd23 = u2h(xd4.y);                             \
    half2_t xd45 = u2h(xd4.z), xd67 = u2h(xd4.w);                             \
    float ex0 = __expf((float)xm01[0] - (float)xd01[0] + c8[0]);              \
    float ex1 = __expf((float)xm01[1] - (float)xd01[1] + c8[1]);              \
    float ex2 = __expf((float)xm23[0] - (float)xd23[0] + c8[2]);              \
    float ex3 = __expf((float)xm23[1] - (float)xd23[1] + c8[3]);              \
    float ex4 = __expf((float)xm45[0] - (float)xd45[0] + c8[4]);              \
    float ex5 = __expf((float)xm45[1] - (float)xd45[1] + c8[5]);              \
    float ex6 = __expf((float)xm67[0] - (float)xd67[0] + c8[6]);              \
    float ex7 = __expf((float)xm67[1] - (float)xd67[1] + c8[7]);              \
    float ssum = ((ex0 + ex1) + (ex2 + ex3)) + ((ex4 + ex5) + (ex6 + ex7));   \
    float rs = __builtin_amdgcn_rcpf(ssum) * evv;                             \
    uint4 qq;                                                                 \
    qq.x = cvt_pk_u(ex0 * rs, ex1 * rs);                                      \
    qq.y = cvt_pk_u(ex2 * rs, ex3 * rs);                                      \
    qq.z = cvt_pk_u(ex4 * rs, ex5 * rs);                                      \
    qq.w = cvt_pk_u(ex6 * rs, ex7 * rs);                                      \
    int vv = l >> 4, jq = (l >> 2) & 3, jl = l & 3;                           \
    char* qb = (XUDs) + wave * 1024 + vv * 256;                               \
    _Pragma("unroll")                                                         \
    for (int m = 0; m < 8; ++m) {                                             \
      unsigned short hv = (unsigned short)((&qq.x)[m >> 1] >> ((m & 1) * 16));\
      int byte = (((m ^ vv) & 7) << 5) + (((jq ^ vv ^ m) & 3) << 3) + jl * 2; \
      *(unsigned short*)(qb + byte) = hv;                                     \
    }                                                                         \
  }

// K2 FUSED: phase 0 = prep (data_h/xu_h/Bt, verbatim k1) -> manual grid
// barrier (ticket counter, memset-zeroed per call; all 512 blocks co-resident
// by capacity: 2/CU x 256 CU, LDS-bound) -> main loop verbatim R18.
__global__ __launch_bounds__(256, 2) void k2_fused(
    const float* __restrict__ data,
    const float* __restrict__ var_u,
    const float* __restrict__ var_w,
    const int* __restrict__ edge_dst,
    const float* __restrict__ edge_vals,
    const float* __restrict__ var_c,
    const float* __restrict__ var_b,
    unsigned short* __restrict__ data_h,
    unsigned short* __restrict__ xu_h,
    unsigned short* __restrict__ Bt,
    unsigned* __restrict__ gsync,
    float* __restrict__ y) {
  extern __shared__ __align__(16) char smem[];
  char* XB0  = smem;           // 2 x 32768 : X' (tr-layout, 2KB/v) / agg reuse
  char* XUD0 = smem + 65536;   // 2 x 4096  : xud records -> Q_B overlay
  char* LIN0 = smem + 73728;   // 4 x 2048  : per-tile dst(1024B) + ev(1024B)

  int tid = threadIdx.x;

  // ================= phase 0: prep (verbatim k1, grid-sized) =================
  {
    float* u_lds = (float*)smem;
    if (blockIdx.x < 128) {
      int t = blockIdx.x * 256 + tid;
      int d = t >> 9, k = t & 511;
      _Float16 h = (_Float16)var_w[k * 64 + d];
      Bt[t] = __builtin_bit_cast(unsigned short, h);
    }
    u_lds[tid] = var_u[tid];
    u_lds[tid + 256] = var_u[tid + 256];
    __syncthreads();
    int v = blockIdx.x * 256 + tid;
    if (v < NV) {
      const float4* dp = (const float4*)(data + v * 64);
      float acc[8];
#pragma unroll
      for (int w = 0; w < 8; ++w) acc[w] = 0.f;
      uint4* ob = (uint4*)(data_h + v * 64);
#pragma unroll
      for (int q = 0; q < 8; ++q) {
        float4 a4 = dp[q * 2], b4 = dp[q * 2 + 1];
        int c0 = q * 8;
#pragma unroll
        for (int w = 0; w < 8; ++w)
          acc[w] += a4.x * u_lds[(c0 + 0) * 8 + w] + a4.y * u_lds[(c0 + 1) * 8 + w]
                  + a4.z * u_lds[(c0 + 2) * 8 + w] + a4.w * u_lds[(c0 + 3) * 8 + w]
                  + b4.x * u_lds[(c0 + 4) * 8 + w] + b4.y * u_lds[(c0 + 5) * 8 + w]
                  + b4.z * u_lds[(c0 + 6) * 8 + w] + b4.w * u_lds[(c0 + 7) * 8 + w];
        uint4 pk;
        pk.x = cvt_pk_u(a4.x, a4.y); pk.y = cvt_pk_u(a4.z, a4.w);
        pk.z = cvt_pk_u(b4.x, b4.y); pk.w = cvt_pk_u(b4.z, b4.w);
        ob[q] = pk;
      }
      uint4 xp;
      xp.x = cvt_pk_u(acc[0], acc[1]); xp.y = cvt_pk_u(acc[2], acc[3]);
      xp.z = cvt_pk_u(acc[4], acc[5]); xp.w = cvt_pk_u(acc[6], acc[7]);
      *(uint4*)(xu_h + v * 8) = xp;
    }
  }
  // ---- manual grid barrier (replay-safe: gsync memset to 0 each call) ----
  __threadfence();              // device-scope release of prep writes
  __syncthreads();              // all waves of block done (incl. their fences)
  if (tid == 0) {
    __hip_atomic_fetch_add(gsync, 1u, __ATOMIC_RELEASE, __HIP_MEMORY_SCOPE_AGENT);
    while (__hip_atomic_load(gsync, __ATOMIC_ACQUIRE, __HIP_MEMORY_SCOPE_AGENT)
           < (unsigned)GRID)
      __builtin_amdgcn_s_sleep(8);
  }
  __syncthreads();              // broadcast release to all waves
  __threadfence();              // acquire side

  // ================= main loop (verbatim R18) =================
  int wave = tid >> 6;
  int l = tid & 63;
  int q4 = l >> 4;          // g (k-quad) / vertex group
  int row = l & 15;         // m (sweep) / A-row, out col (phase C)
  int col = row + wave * 16;

  uint4 btf[16];
#pragma unroll
  for (int ks = 0; ks < 16; ++ks)
    btf[ks] = *(const uint4*)(Bt + (col * 512 + ks * 32 + q4 * 8));
  float c8[8];
#pragma unroll
  for (int m = 0; m < 8; ++m) c8[m] = var_c[m];
  float bias = var_b[col];

#define LIN_DMA(SL, TS)                                                        \
  { char* lb_ = LIN0 + (SL) * 2048;                                            \
    if ((wave & 1) == 0)                                                       \
      load16_to_lds(edge_dst + (size_t)(TS) * 256 + l * 4, lb_);               \
    else                                                                       \
      load16_to_lds(edge_vals + (size_t)(TS) * 256 + l * 4, lb_ + 1024); }
#define XUD_DMA(SL, LSL)                                                       \
  { const int* ld_ = (const int*)(LIN0 + (LSL) * 2048);                        \
    int dv_ = ld_[wave * 64 + l];                                              \
    load16_to_lds(xu_h + (size_t)dv_ * 8, XUD0 + (SL) * 4096 + wave * 1024); }
  // X' chunk permutation: dest chunk d (within v) = h + idx*2 + g*8 + cb*32
  // holds X[j = g*4+idx][cb*16 + (h? 8..15 : 0..7)]  (tr_b16-readable layout)
#define X_DMA(SL, LSL)                                                         \
  { const int* ld_ = (const int*)(LIN0 + (LSL) * 2048);                        \
    int j_ = ((l >> 3) & 3) * 4 + ((l >> 1) & 3);                              \
    int ch0_ = ((l >> 5) << 1) | (l & 1);                                      \
    _Pragma("unroll")                                                          \
    for (int s_ = 0; s_ < 8; ++s_) {                                           \
      int dv_ = ld_[wave * 64 + (s_ >> 1) * 16 + j_];                          \
      int ch_ = ch0_ + (s_ & 1) * 4;                                           \
      load16_to_lds(data_h + (size_t)dv_ * 64 + ch_ * 8,                       \
                    XB0 + (SL) * 32768 + wave * 8192 + s_ * 1024); } }

  int t0 = blockIdx.x;
  int tG1 = (t0 + GRID < NTILE) ? t0 + GRID : t0;
  int tG2 = (t0 + 2 * GRID < NTILE) ? t0 + 2 * GRID : t0;
  FENCE;
  LIN_DMA(0, t0);
  LIN_DMA(1, tG1);
  LIN_DMA(2, tG2);
  FENCE;
  uint4 xsA = *(const uint4*)(xu_h + ((size_t)t0 * 16 + wave * 4 + q4) * 8);
  uint4 xsB = *(const uint4*)(xu_h + ((size_t)tG1 * 16 + wave * 4 + q4) * 8);
  VMWAIT(0);
  __builtin_amdgcn_s_barrier();
  FENCE;
  XUD_DMA(0, 0);
  X_DMA(0, 0);
  FENCE;
  VMWAIT(0);
  __builtin_amdgcn_s_barrier();
  // prologue prepass(t0): q(t0) into XUD slot 0 (wave-private)
  PREPASS(XUD0, LIN0, xsA);
  LGKM0;

  int kc = 0;
  for (int t = t0; t < NTILE; t += GRID, ++kc) {
    int slc = kc & 1;
    int sl1 = (kc + 1) & 1, lsl1 = (kc + 1) & 3, lsl3 = (kc + 3) & 3;
    int t2c = (t + 2 * GRID < NTILE) ? t + 2 * GRID : t;
    int t3c = (t + 3 * GRID < NTILE) ? t + 3 * GRID : t;
    char* XBt = XB0 + slc * 32768;
    char* XUDt = XUD0 + slc * 4096;
    char* XUDn = XUD0 + sl1 * 4096;
    const char* LINn = LIN0 + lsl1 * 2048;

    // step1: stage next tile's xud + X' (9 DMAs; land during this iteration)
    FENCE;
    XUD_DMA(sl1, lsl1);
    X_DMA(sl1, lsl1);
    FENCE;

    // sweep(t): q(t) precomputed last iteration -> starts immediately.
    // per vertex agg[m][c] = Q[m][j] @ X[j][c] via MFMA 16x16x16.
    {
      uint2 qfr[4];
#pragma unroll
      for (int vv = 0; vv < 4; ++vv) {
        int srow = (row ^ vv) & 7;
        int gsl = (q4 ^ vv ^ row) & 3;
        qfr[vv] = *(const uint2*)(XUDt + wave * 1024 + vv * 256 + srow * 32 + gsl * 8);
      }
      unsigned xbase = lds_off(XBt + wave * 8192) + l * 8;
      uint2 trd[16];
#pragma unroll
      for (int vv = 0; vv < 4; ++vv)
#pragma unroll
        for (int cb = 0; cb < 4; ++cb) {
          unsigned a_ = xbase + vv * 2048 + cb * 512;
          asm volatile("ds_read_b64_tr_b16 %0, %1"
                       : "=v"(trd[vv * 4 + cb]) : "v"(a_) : "memory");
        }
      LGKM0;
      __builtin_amdgcn_sched_barrier(0);
      f32x4 D[16];
      __builtin_amdgcn_s_setprio(1);
#pragma unroll
      for (int vv = 0; vv < 4; ++vv)
#pragma unroll
        for (int cb = 0; cb < 4; ++cb) {
          f32x4 z = {0.f, 0.f, 0.f, 0.f};
          D[vv * 4 + cb] = __builtin_amdgcn_mfma_f32_16x16x16f16(
              __builtin_bit_cast(half4_t, trd[vv * 4 + cb]),
              __builtin_bit_cast(half4_t, qfr[vv]), z, 0, 0, 0);
        }
      __builtin_amdgcn_s_setprio(0);
      // pack + store agg (halves): lanes m = row < 8 valid
      if (row < 8) {
#pragma unroll
        for (int vv = 0; vv < 4; ++vv) {
          int vg = wave * 4 + vv;
          char* ab = XBt + vg * 2048;
#pragma unroll
          for (int cb = 0; cb < 4; ++cb) {
            f32x4 d4 = D[vv * 4 + cb];
            uint2 w2;
            w2.x = cvt_pk_u(d4[0], d4[1]);
            w2.y = cvt_pk_u(d4[2], d4[3]);
            int byte = (row * 128 + cb * 32 + q4 * 8) ^ ((vg & 7) << 4)
                       ^ ((row & 3) << 5);
            *(uint2*)(ab + byte) = w2;
          }
        }
      }
    }

    // prepass(t+1): xud(t+1) retired by VMWAIT(8) (retires y(t-1)x4 + xud;
    // X(t+1)'s 8 DMAs stay in flight). Wave-private q write into slot sl1.
    VMWAIT(8);
    PREPASS(XUDn, LINn, xsB);

    // mid: future xs reg load + lin for t+3G (after VMWAIT(8) to keep ledger)
    FENCE;
    uint4 xsC = *(const uint4*)(xu_h + ((size_t)t2c * 16 + wave * 4 + q4) * 8);
    FENCE;
    LIN_DMA(lsl3, t3c);
    FENCE;

    LGKM0;
    __builtin_amdgcn_s_barrier();   // B1: agg visible to all waves

    // phase C: 16x64 tile; wave w owns cols [16w,16w+16). Dual accumulators.
    {
      f32x4 C0 = {0.f, 0.f, 0.f, 0.f};
      f32x4 C1 = {0.f, 0.f, 0.f, 0.f};
      __builtin_amdgcn_s_setprio(1);
#pragma unroll
      for (int ks2 = 0; ks2 < 8; ++ks2) {
        int ka = 2 * ks2, kb = 2 * ks2 + 1;
        int boa = (ka * 64 + q4 * 16) ^ ((row & 7) << 4) ^ (((ka >> 1) & 3) << 5);
        int bob = (kb * 64 + q4 * 16) ^ ((row & 7) << 4) ^ (((kb >> 1) & 3) << 5);
        half8_t afa = *(const half8_t*)(XBt + row * 2048 + boa);
        half8_t afb = *(const half8_t*)(XBt + row * 2048 + bob);
        C0 = __builtin_amdgcn_mfma_f32_16x16x32_f16(
            afa, __builtin_bit_cast(half8_t, btf[ka]), C0, 0, 0, 0);
        C1 = __builtin_amdgcn_mfma_f32_16x16x32_f16(
            afb, __builtin_bit_cast(half8_t, btf[kb]), C1, 0, 0, 0);
      }
      __builtin_amdgcn_s_setprio(0);
#pragma unroll
      for (int i = 0; i < 4; ++i)
        y[(size_t)(t * 16 + q4 * 4 + i) * 64 + col] = C0[i] + C1[i] + bias;
    }
    LGKM0;       // phase-C agg reads retired before next iter's X DMA reuse
    VMWAIT(4);   // everything except the 4 y-stores retired
    __builtin_amdgcn_s_barrier();   // B2

    xsB = xsC;
    (void)xsA;
  }
  VMWAIT(0);     // drain tail (incl. dummy prefetch DMAs) before exit
#undef LIN_DMA
#undef XUD_DMA
#undef X_DMA
}

extern "C" void kernel_launch(void* const* d_in, const int* in_sizes, int n_in,
                              void* d_out, int out_size, void* d_ws, size_t ws_size,
                              hipStream_t stream) {
  const float* data      = (const float*)d_in[0];
  // d_in[1] = edge_src: structurally repeat(arange(V),16) -> implicit, unused
  const int*   edge_dst  = (const int*)d_in[2];
  const float* edge_vals = (const float*)d_in[3];
  const float* var_u     = (const float*)d_in[4];
  const float* var_c     = (const float*)d_in[5];
  const float* var_w     = (const float*)d_in[6];
  const float* var_b     = (const float*)d_in[7];
  float* y = (float*)d_out;

  char* ws = (char*)d_ws;
  unsigned short* data_h = (unsigned short*)ws;                  // 12,800,000 B
  unsigned short* xu_h   = (unsigned short*)(ws + 12800000);     //  1,600,000 B
  unsigned short* Bt     = (unsigned short*)(ws + 14400000);     //     65,536 B
  unsigned*       gsync  = (unsigned*)(ws + 14465536);           //          4 B

  hipFuncSetAttribute((const void*)k2_fused,
                      hipFuncAttributeMaxDynamicSharedMemorySize, LDSZ);

  hipMemsetAsync((void*)gsync, 0, 4, stream);   // re-zero barrier each call
  hipLaunchKernelGGL(k2_fused, dim3(GRID), dim3(256), LDSZ, stream,
                     data, var_u, var_w, edge_dst, edge_vals, var_c, var_b,
                     data_h, xu_h, Bt, gsync, y);
}

// Round 21
// 71.074 us; speedup vs baseline: 3.6277x; 3.6277x over previous
//
#include <hip/hip_runtime.h>

typedef _Float16 half2_t __attribute__((ext_vector_type(2)));
typedef _Float16 half4_t __attribute__((ext_vector_type(4)));
typedef _Float16 half8_t __attribute__((ext_vector_type(8)));
typedef __attribute__((ext_vector_type(4))) float f32x4;

#define NV 100000
#define NTILE 6250      // 16 vertices per tile
#define GRID 512        // 2 blocks/CU target, persistent grid-stride
#define LDSZ 81920      // 64K X dbuf + 8K xud/qB dbuf + 8K lin quad

#define VMWAIT(N) asm volatile("s_waitcnt vmcnt(" #N ")" ::: "memory")
#define LGKM0     asm volatile("s_waitcnt lgkmcnt(0)" ::: "memory")
#define FENCE     asm volatile("" ::: "memory")

__device__ __forceinline__ unsigned cvt_pk_u(float a, float b) {
  auto h = __builtin_amdgcn_cvt_pkrtz(a, b);
  return __builtin_bit_cast(unsigned, h);
}
__device__ __forceinline__ half2_t u2h(unsigned u) { return __builtin_bit_cast(half2_t, u); }
// generic -> 32-bit LDS offset (for inline-asm ds ops)
__device__ __forceinline__ unsigned lds_off(const void* p) {
  return (unsigned)(size_t)(const __attribute__((address_space(3))) char*)p;
}
// async global->LDS: lds dest = wave-uniform base + lane*16 (HW rule)
__device__ __forceinline__ void load16_to_lds(const void* g, void* s) {
  __builtin_amdgcn_global_load_lds(
      (const __attribute__((address_space(1))) unsigned int*)g,
      (__attribute__((address_space(3))) unsigned int*)s, 16, 0, 0);
}

// K1 (k0 fused): coalesced re-lane. Wave covers 64 vertices; per iteration
// lane (v=l>>4, c4=l&15) loads float4 of row v at chunk c4 (4KB contiguous
// per wave-iter). x_u finished via 16-lane shfl_xor butterfly. u_lds stored
// TRANSPOSED [w][c] (banks: 4*c4 stride -> 2-way max, free).
__global__ __launch_bounds__(256) void k1_prep(const float* __restrict__ data,
                                               const float* __restrict__ var_u,
                                               const float* __restrict__ var_w,
                                               unsigned short* __restrict__ data_h,
                                               unsigned short* __restrict__ xu_h,
                                               unsigned short* __restrict__ Bt) {
  __shared__ float u_lds[512];   // [w][c]: u_lds[w*64+c] = var_u[c*8+w]
  int tid = threadIdx.x;
  // fused k0: Bt transpose-cast (32768 elems over first 128 blocks)
  if (blockIdx.x < 128) {
    int t = blockIdx.x * 256 + tid;
    int d = t >> 9, k = t & 511;
    _Float16 h = (_Float16)var_w[k * 64 + d];
    Bt[t] = __builtin_bit_cast(unsigned short, h);
  }
  u_lds[(tid & 7) * 64 + (tid >> 3)] = var_u[tid];
  {
    int e2 = tid + 256;
    u_lds[(e2 & 7) * 64 + (e2 >> 3)] = var_u[e2];
  }
  __syncthreads();
  int wave = tid >> 6, l = tid & 63;
  int vb = blockIdx.x * 256 + wave * 64;
  int vsub = l >> 4;      // vertex within 4-group
  int c4 = l & 15;        // float4 chunk within row
#pragma unroll 4
  for (int it = 0; it < 16; ++it) {
    int v = vb + it * 4 + vsub;
    float4 d4 = {0.f, 0.f, 0.f, 0.f};
    if (v < NV) d4 = *(const float4*)(data + (size_t)v * 64 + c4 * 4);
    float acc[8];
#pragma unroll
    for (int w = 0; w < 8; ++w)
      acc[w] = d4.x * u_lds[w * 64 + c4 * 4 + 0] + d4.y * u_lds[w * 64 + c4 * 4 + 1]
             + d4.z * u_lds[w * 64 + c4 * 4 + 2] + d4.w * u_lds[w * 64 + c4 * 4 + 3];
#pragma unroll
    for (int mk = 1; mk < 16; mk <<= 1)
#pragma unroll
      for (int w = 0; w < 8; ++w) acc[w] += __shfl_xor(acc[w], mk);
    if (v < NV) {
      uint2 pk;
      pk.x = cvt_pk_u(d4.x, d4.y);
      pk.y = cvt_pk_u(d4.z, d4.w);
      *(uint2*)(data_h + (size_t)v * 64 + c4 * 4) = pk;
      if (c4 == 0) {
        uint4 xp;
        xp.x = cvt_pk_u(acc[0], acc[1]); xp.y = cvt_pk_u(acc[2], acc[3]);
        xp.z = cvt_pk_u(acc[4], acc[5]); xp.w = cvt_pk_u(acc[6], acc[7]);
        *(uint4*)(xu_h + (size_t)v * 8) = xp;
      }
    }
  }
}

// PREPASS: per-edge in-lane softmax over m; q -> swizzled Q_B overlay on the
// xud records of slot XUDs (wave-private region).  (verbatim R12 math)
#define PREPASS(XUDs, LINs, XS)                                               \
  {                                                                           \
    uint4 xd4 = *(const uint4*)((XUDs) + (wave * 64 + l) * 16);               \
    float evv = ((const float*)((LINs) + 1024))[wave * 64 + l];               \
    half2_t xm01 = u2h((XS).x), xm23 = u2h((XS).y);                           \
    half2_t xm45 = u2h((XS).z), xm67 = u2h((XS).w);                           \
    half2_t xd01 = u2h(xd4.x), xd23 = u2h(xd4.y);                             \
    half2_t xd45 = u2h(xd4.z), xd67 = u2h(xd4.w);                             \
    float ex0 = __expf((float)xm01[0] - (float)xd01[0] + c8[0]);              \
    float ex1 = __expf((float)xm01[1] - (float)xd01[1] + c8[1]);              \
    float ex2 = __expf((float)xm23[0] - (float)xd23[0] + c8[2]);              \
    float ex3 = __expf((float)xm23[1] - (float)xd23[1] + c8[3]);              \
    float ex4 = __expf((float)xm45[0] - (float)xd45[0] + c8[4]);              \
    float ex5 = __expf((float)xm45[1] - (float)xd45[1] + c8[5]);              \
    float ex6 = __expf((float)xm67[0] - (float)xd67[0] + c8[6]);              \
    float ex7 = __expf((float)xm67[1] - (float)xd67[1] + c8[7]);              \
    float ssum = ((ex0 + ex1) + (ex2 + ex3)) + ((ex4 + ex5) + (ex6 + ex7));   \
    float rs = __builtin_amdgcn_rcpf(ssum) * evv;                             \
    uint4 qq;                                                                 \
    qq.x = cvt_pk_u(ex0 * rs, ex1 * rs);                                      \
    qq.y = cvt_pk_u(ex2 * rs, ex3 * rs);                                      \
    qq.z = cvt_pk_u(ex4 * rs, ex5 * rs);                                      \
    qq.w = cvt_pk_u(ex6 * rs, ex7 * rs);                                      \
    int vv = l >> 4, jq = (l >> 2) & 3, jl = l & 3;                           \
    char* qb = (XUDs) + wave * 1024 + vv * 256;                               \
    _Pragma("unroll")                                                         \
    for (int m = 0; m < 8; ++m) {                                             \
      unsigned short hv = (unsigned short)((&qq.x)[m >> 1] >> ((m & 1) * 16));\
      int byte = (((m ^ vv) & 7) << 5) + (((jq ^ vv ^ m) & 3) << 3) + jl * 2; \
      *(unsigned short*)(qb + byte) = hv;                                     \
    }                                                                         \
  }

// K2: verbatim R18 (best measured 52.5us): persistent; 16-v tiles; prepass
// hoisted one iteration; aggregation on matrix cores (tr-read X-frags,
// 16x16x16); phase C 16x64 via 16x16x32, dual accumulators, setprio.
__global__ __launch_bounds__(256, 2) void k2_main(
    const unsigned short* __restrict__ data_h,
    const unsigned short* __restrict__ xu_h,
    const int* __restrict__ edge_dst,
    const float* __restrict__ edge_vals,
    const unsigned short* __restrict__ Bt,
    const float* __restrict__ var_c,
    const float* __restrict__ var_b,
    float* __restrict__ y) {
  extern __shared__ __align__(16) char smem[];
  char* XB0  = smem;           // 2 x 32768 : X' (tr-layout, 2KB/v) / agg reuse
  char* XUD0 = smem + 65536;   // 2 x 4096  : xud records -> Q_B overlay
  char* LIN0 = smem + 73728;   // 4 x 2048  : per-tile dst(1024B) + ev(1024B)

  int tid = threadIdx.x;
  int wave = tid >> 6;
  int l = tid & 63;
  int q4 = l >> 4;          // g (k-quad) / vertex group
  int row = l & 15;         // m (sweep) / A-row, out col (phase C)
  int col = row + wave * 16;

  uint4 btf[16];
#pragma unroll
  for (int ks = 0; ks < 16; ++ks)
    btf[ks] = *(const uint4*)(Bt + (col * 512 + ks * 32 + q4 * 8));
  float c8[8];
#pragma unroll
  for (int m = 0; m < 8; ++m) c8[m] = var_c[m];
  float bias = var_b[col];

#define LIN_DMA(SL, TS)                                                        \
  { char* lb_ = LIN0 + (SL) * 2048;                                            \
    if ((wave & 1) == 0)                                                       \
      load16_to_lds(edge_dst + (size_t)(TS) * 256 + l * 4, lb_);               \
    else                                                                       \
      load16_to_lds(edge_vals + (size_t)(TS) * 256 + l * 4, lb_ + 1024); }
#define XUD_DMA(SL, LSL)                                                       \
  { const int* ld_ = (const int*)(LIN0 + (LSL) * 2048);                        \
    int dv_ = ld_[wave * 64 + l];                                              \
    load16_to_lds(xu_h + (size_t)dv_ * 8, XUD0 + (SL) * 4096 + wave * 1024); }
  // X' chunk permutation: dest chunk d (within v) = h + idx*2 + g*8 + cb*32
  // holds X[j = g*4+idx][cb*16 + (h? 8..15 : 0..7)]  (tr_b16-readable layout)
#define X_DMA(SL, LSL)                                                         \
  { const int* ld_ = (const int*)(LIN0 + (LSL) * 2048);                        \
    int j_ = ((l >> 3) & 3) * 4 + ((l >> 1) & 3);                              \
    int ch0_ = ((l >> 5) << 1) | (l & 1);                                      \
    _Pragma("unroll")                                                          \
    for (int s_ = 0; s_ < 8; ++s_) {                                           \
      int dv_ = ld_[wave * 64 + (s_ >> 1) * 16 + j_];                          \
      int ch_ = ch0_ + (s_ & 1) * 4;                                           \
      load16_to_lds(data_h + (size_t)dv_ * 64 + ch_ * 8,                       \
                    XB0 + (SL) * 32768 + wave * 8192 + s_ * 1024); } }

  int t0 = blockIdx.x;
  int tG1 = (t0 + GRID < NTILE) ? t0 + GRID : t0;
  int tG2 = (t0 + 2 * GRID < NTILE) ? t0 + 2 * GRID : t0;
  FENCE;
  LIN_DMA(0, t0);
  LIN_DMA(1, tG1);
  LIN_DMA(2, tG2);
  FENCE;
  uint4 xsA = *(const uint4*)(xu_h + ((size_t)t0 * 16 + wave * 4 + q4) * 8);
  uint4 xsB = *(const uint4*)(xu_h + ((size_t)tG1 * 16 + wave * 4 + q4) * 8);
  VMWAIT(0);
  __builtin_amdgcn_s_barrier();
  FENCE;
  XUD_DMA(0, 0);
  X_DMA(0, 0);
  FENCE;
  VMWAIT(0);
  __builtin_amdgcn_s_barrier();
  // prologue prepass(t0): q(t0) into XUD slot 0 (wave-private)
  PREPASS(XUD0, LIN0, xsA);
  LGKM0;

  int kc = 0;
  for (int t = t0; t < NTILE; t += GRID, ++kc) {
    int slc = kc & 1;
    int sl1 = (kc + 1) & 1, lsl1 = (kc + 1) & 3, lsl3 = (kc + 3) & 3;
    int t2c = (t + 2 * GRID < NTILE) ? t + 2 * GRID : t;
    int t3c = (t + 3 * GRID < NTILE) ? t + 3 * GRID : t;
    char* XBt = XB0 + slc * 32768;
    char* XUDt = XUD0 + slc * 4096;
    char* XUDn = XUD0 + sl1 * 4096;
    const char* LINn = LIN0 + lsl1 * 2048;

    // step1: stage next tile's xud + X' (9 DMAs; land during this iteration)
    FENCE;
    XUD_DMA(sl1, lsl1);
    X_DMA(sl1, lsl1);
    FENCE;

    // sweep(t): q(t) precomputed last iteration -> starts immediately.
    // per vertex agg[m][c] = Q[m][j] @ X[j][c] via MFMA 16x16x16.
    {
      uint2 qfr[4];
#pragma unroll
      for (int vv = 0; vv < 4; ++vv) {
        int srow = (row ^ vv) & 7;
        int gsl = (q4 ^ vv ^ row) & 3;
        qfr[vv] = *(const uint2*)(XUDt + wave * 1024 + vv * 256 + srow * 32 + gsl * 8);
      }
      unsigned xbase = lds_off(XBt + wave * 8192) + l * 8;
      uint2 trd[16];
#pragma unroll
      for (int vv = 0; vv < 4; ++vv)
#pragma unroll
        for (int cb = 0; cb < 4; ++cb) {
          unsigned a_ = xbase + vv * 2048 + cb * 512;
          asm volatile("ds_read_b64_tr_b16 %0, %1"
                       : "=v"(trd[vv * 4 + cb]) : "v"(a_) : "memory");
        }
      LGKM0;
      __builtin_amdgcn_sched_barrier(0);
      f32x4 D[16];
      __builtin_amdgcn_s_setprio(1);
#pragma unroll
      for (int vv = 0; vv < 4; ++vv)
#pragma unroll
        for (int cb = 0; cb < 4; ++cb) {
          f32x4 z = {0.f, 0.f, 0.f, 0.f};
          D[vv * 4 + cb] = __builtin_amdgcn_mfma_f32_16x16x16f16(
              __builtin_bit_cast(half4_t, trd[vv * 4 + cb]),
              __builtin_bit_cast(half4_t, qfr[vv]), z, 0, 0, 0);
        }
      __builtin_amdgcn_s_setprio(0);
      // pack + store agg (halves): lanes m = row < 8 valid
      if (row < 8) {
#pragma unroll
        for (int vv = 0; vv < 4; ++vv) {
          int vg = wave * 4 + vv;
          char* ab = XBt + vg * 2048;
#pragma unroll
          for (int cb = 0; cb < 4; ++cb) {
            f32x4 d4 = D[vv * 4 + cb];
            uint2 w2;
            w2.x = cvt_pk_u(d4[0], d4[1]);
            w2.y = cvt_pk_u(d4[2], d4[3]);
            int byte = (row * 128 + cb * 32 + q4 * 8) ^ ((vg & 7) << 4)
                       ^ ((row & 3) << 5);
            *(uint2*)(ab + byte) = w2;
          }
        }
      }
    }

    // prepass(t+1): xud(t+1) retired by VMWAIT(8) (retires y(t-1)x4 + xud;
    // X(t+1)'s 8 DMAs stay in flight). Wave-private q write into slot sl1.
    VMWAIT(8);
    PREPASS(XUDn, LINn, xsB);

    // mid: future xs reg load + lin for t+3G (after VMWAIT(8) to keep ledger)
    FENCE;
    uint4 xsC = *(const uint4*)(xu_h + ((size_t)t2c * 16 + wave * 4 + q4) * 8);
    FENCE;
    LIN_DMA(lsl3, t3c);
    FENCE;

    LGKM0;
    __builtin_amdgcn_s_barrier();   // B1: agg visible to all waves

    // phase C: 16x64 tile; wave w owns cols [16w,16w+16). Dual accumulators.
    {
      f32x4 C0 = {0.f, 0.f, 0.f, 0.f};
      f32x4 C1 = {0.f, 0.f, 0.f, 0.f};
      __builtin_amdgcn_s_setprio(1);
#pragma unroll
      for (int ks2 = 0; ks2 < 8; ++ks2) {
        int ka = 2 * ks2, kb = 2 * ks2 + 1;
        int boa = (ka * 64 + q4 * 16) ^ ((row & 7) << 4) ^ (((ka >> 1) & 3) << 5);
        int bob = (kb * 64 + q4 * 16) ^ ((row & 7) << 4) ^ (((kb >> 1) & 3) << 5);
        half8_t afa = *(const half8_t*)(XBt + row * 2048 + boa);
        half8_t afb = *(const half8_t*)(XBt + row * 2048 + bob);
        C0 = __builtin_amdgcn_mfma_f32_16x16x32_f16(
            afa, __builtin_bit_cast(half8_t, btf[ka]), C0, 0, 0, 0);
        C1 = __builtin_amdgcn_mfma_f32_16x16x32_f16(
            afb, __builtin_bit_cast(half8_t, btf[kb]), C1, 0, 0, 0);
      }
      __builtin_amdgcn_s_setprio(0);
#pragma unroll
      for (int i = 0; i < 4; ++i)
        y[(size_t)(t * 16 + q4 * 4 + i) * 64 + col] = C0[i] + C1[i] + bias;
    }
    LGKM0;       // phase-C agg reads retired before next iter's X DMA reuse
    VMWAIT(4);   // everything except the 4 y-stores retired
    __builtin_amdgcn_s_barrier();   // B2

    xsB = xsC;
    (void)xsA;
  }
  VMWAIT(0);     // drain tail (incl. dummy prefetch DMAs) before exit
#undef LIN_DMA
#undef XUD_DMA
#undef X_DMA
}

extern "C" void kernel_launch(void* const* d_in, const int* in_sizes, int n_in,
                              void* d_out, int out_size, void* d_ws, size_t ws_size,
                              hipStream_t stream) {
  const float* data      = (const float*)d_in[0];
  // d_in[1] = edge_src: structurally repeat(arange(V),16) -> implicit, unused
  const int*   edge_dst  = (const int*)d_in[2];
  const float* edge_vals = (const float*)d_in[3];
  const float* var_u     = (const float*)d_in[4];
  const float* var_c     = (const float*)d_in[5];
  const float* var_w     = (const float*)d_in[6];
  const float* var_b     = (const float*)d_in[7];
  float* y = (float*)d_out;

  char* ws = (char*)d_ws;
  unsigned short* data_h = (unsigned short*)ws;                  // 12,800,000 B
  unsigned short* xu_h   = (unsigned short*)(ws + 12800000);     //  1,600,000 B
  unsigned short* Bt     = (unsigned short*)(ws + 14400000);     //     65,536 B

  hipFuncSetAttribute((const void*)k2_main,
                      hipFuncAttributeMaxDynamicSharedMemorySize, LDSZ);

  hipLaunchKernelGGL(k1_prep, dim3((NV + 255) / 256), dim3(256), 0, stream,
                     data, var_u, var_w, data_h, xu_h, Bt);
  hipLaunchKernelGGL(k2_main, dim3(GRID), dim3(256), LDSZ, stream,
                     data_h, xu_h, edge_dst, edge_vals, Bt, var_c, var_b, y);
}

// Round 22
// 68.922 us; speedup vs baseline: 3.7409x; 1.0312x over previous
//
#include <hip/hip_runtime.h>

typedef _Float16 half2_t __attribute__((ext_vector_type(2)));
typedef _Float16 half4_t __attribute__((ext_vector_type(4)));
typedef _Float16 half8_t __attribute__((ext_vector_type(8)));
typedef __attribute__((ext_vector_type(4))) float f32x4;

#define NV 100000
#define NTILE 6250      // 16 vertices per tile
#define GRID 512        // 2 blocks/CU, persistent grid-stride
#define LDSZ 81920      // 64K X dbuf + 8K xud/qB dbuf + 8K lin quad

#define VMWAIT(N) asm volatile("s_waitcnt vmcnt(" #N ")" ::: "memory")
#define LGKM0     asm volatile("s_waitcnt lgkmcnt(0)" ::: "memory")
#define FENCE     asm volatile("" ::: "memory")

__device__ __forceinline__ unsigned cvt_pk_u(float a, float b) {
  auto h = __builtin_amdgcn_cvt_pkrtz(a, b);
  return __builtin_bit_cast(unsigned, h);
}
__device__ __forceinline__ half2_t u2h(unsigned u) { return __builtin_bit_cast(half2_t, u); }
// generic -> 32-bit LDS offset (for inline-asm ds ops)
__device__ __forceinline__ unsigned lds_off(const void* p) {
  return (unsigned)(size_t)(const __attribute__((address_space(3))) char*)p;
}
// async global->LDS: lds dest = wave-uniform base + lane*16 (HW rule)
__device__ __forceinline__ void load16_to_lds(const void* g, void* s) {
  __builtin_amdgcn_global_load_lds(
      (const __attribute__((address_space(1))) unsigned int*)g,
      (__attribute__((address_space(3))) unsigned int*)s, 16, 0, 0);
}

// K1 (k0 fused): blocks 0..127 also emit Bt[d][k] = fp16(var_w[k*64+d]);
// all blocks: data_h[v][64] fp16 (128B rows) ; xu_h[v][8] fp16 (16B records)
__global__ __launch_bounds__(256) void k1_prep(const float* __restrict__ data,
                                               const float* __restrict__ var_u,
                                               const float* __restrict__ var_w,
                                               unsigned short* __restrict__ data_h,
                                               unsigned short* __restrict__ xu_h,
                                               unsigned short* __restrict__ Bt) {
  __shared__ float u_lds[512];
  int tid = threadIdx.x;
  // fused k0: Bt transpose-cast (32768 elems over first 128 blocks)
  if (blockIdx.x < 128) {
    int t = blockIdx.x * 256 + tid;
    int d = t >> 9, k = t & 511;
    _Float16 h = (_Float16)var_w[k * 64 + d];
    Bt[t] = __builtin_bit_cast(unsigned short, h);
  }
  u_lds[tid] = var_u[tid];
  u_lds[tid + 256] = var_u[tid + 256];
  __syncthreads();
  int v = blockIdx.x * 256 + tid;
  if (v >= NV) return;
  const float4* dp = (const float4*)(data + v * 64);
  float acc[8];
#pragma unroll
  for (int w = 0; w < 8; ++w) acc[w] = 0.f;
  uint4* ob = (uint4*)(data_h + v * 64);
#pragma unroll
  for (int q = 0; q < 8; ++q) {
    float4 a4 = dp[q * 2], b4 = dp[q * 2 + 1];
    int c0 = q * 8;
#pragma unroll
    for (int w = 0; w < 8; ++w)
      acc[w] += a4.x * u_lds[(c0 + 0) * 8 + w] + a4.y * u_lds[(c0 + 1) * 8 + w]
              + a4.z * u_lds[(c0 + 2) * 8 + w] + a4.w * u_lds[(c0 + 3) * 8 + w]
              + b4.x * u_lds[(c0 + 4) * 8 + w] + b4.y * u_lds[(c0 + 5) * 8 + w]
              + b4.z * u_lds[(c0 + 6) * 8 + w] + b4.w * u_lds[(c0 + 7) * 8 + w];
    uint4 pk;
    pk.x = cvt_pk_u(a4.x, a4.y); pk.y = cvt_pk_u(a4.z, a4.w);
    pk.z = cvt_pk_u(b4.x, b4.y); pk.w = cvt_pk_u(b4.z, b4.w);
    ob[q] = pk;
  }
  uint4 xp;
  xp.x = cvt_pk_u(acc[0], acc[1]); xp.y = cvt_pk_u(acc[2], acc[3]);
  xp.z = cvt_pk_u(acc[4], acc[5]); xp.w = cvt_pk_u(acc[6], acc[7]);
  *(uint4*)(xu_h + v * 8) = xp;
}

// PREPASS: per-edge in-lane softmax over m; q -> swizzled Q_B overlay on the
// xud records of slot XUDs (wave-private region).  (verbatim R12 math)
#define PREPASS(XUDs, LINs, XS)                                               \
  {                                                                           \
    uint4 xd4 = *(const uint4*)((XUDs) + (wave * 64 + l) * 16);               \
    float evv = ((const float*)((LINs) + 1024))[wave * 64 + l];               \
    half2_t xm01 = u2h((XS).x), xm23 = u2h((XS).y);                           \
    half2_t xm45 = u2h((XS).z), xm67 = u2h((XS).w);                           \
    half2_t xd01 = u2h(xd4.x), xd23 = u2h(xd4.y);                             \
    half2_t xd45 = u2h(xd4.z), xd67 = u2h(xd4.w);                             \
    float ex0 = __expf((float)xm01[0] - (float)xd01[0] + c8[0]);              \
    float ex1 = __expf((float)xm01[1] - (float)xd01[1] + c8[1]);              \
    float ex2 = __expf((float)xm23[0] - (float)xd23[0] + c8[2]);              \
    float ex3 = __expf((float)xm23[1] - (float)xd23[1] + c8[3]);              \
    float ex4 = __expf((float)xm45[0] - (float)xd45[0] + c8[4]);              \
    float ex5 = __expf((float)xm45[1] - (float)xd45[1] + c8[5]);              \
    float ex6 = __expf((float)xm67[0] - (float)xd67[0] + c8[6]);              \
    float ex7 = __expf((float)xm67[1] - (float)xd67[1] + c8[7]);              \
    float ssum = ((ex0 + ex1) + (ex2 + ex3)) + ((ex4 + ex5) + (ex6 + ex7));   \
    float rs = __builtin_amdgcn_rcpf(ssum) * evv;                             \
    uint4 qq;                                                                 \
    qq.x = cvt_pk_u(ex0 * rs, ex1 * rs);                                      \
    qq.y = cvt_pk_u(ex2 * rs, ex3 * rs);                                      \
    qq.z = cvt_pk_u(ex4 * rs, ex5 * rs);                                      \
    qq.w = cvt_pk_u(ex6 * rs, ex7 * rs);                                      \
    int vv = l >> 4, jq = (l >> 2) & 3, jl = l & 3;                           \
    char* qb = (XUDs) + wave * 1024 + vv * 256;                               \
    _Pragma("unroll")                                                         \
    for (int m = 0; m < 8; ++m) {                                             \
      unsigned short hv = (unsigned short)((&qq.x)[m >> 1] >> ((m & 1) * 16));\
      int byte = (((m ^ vv) & 7) << 5) + (((jq ^ vv ^ m) & 3) << 3) + jl * 2; \
      *(unsigned short*)(qb + byte) = hv;                                     \
    }                                                                         \
  }

// K2: R12/R17 structure + PREPASS HOISTED one iteration ahead: iteration t
// runs sweep(t) immediately after B2 (q(t) precomputed), then prepass(t+1)
// under VMWAIT(8) (retires y(t-1)x4 + xud(t+1); X(t+1) stays in flight).
__global__ __launch_bounds__(256, 2) void k2_main(
    const unsigned short* __restrict__ data_h,
    const unsigned short* __restrict__ xu_h,
    const int* __restrict__ edge_dst,
    const float* __restrict__ edge_vals,
    const unsigned short* __restrict__ Bt,
    const float* __restrict__ var_c,
    const float* __restrict__ var_b,
    float* __restrict__ y) {
  extern __shared__ __align__(16) char smem[];
  char* XB0  = smem;           // 2 x 32768 : X' (tr-layout, 2KB/v) / agg reuse
  char* XUD0 = smem + 65536;   // 2 x 4096  : xud records -> Q_B overlay
  char* LIN0 = smem + 73728;   // 4 x 2048  : per-tile dst(1024B) + ev(1024B)

  int tid = threadIdx.x;
  int wave = tid >> 6;
  int l = tid & 63;
  int q4 = l >> 4;          // g (k-quad) / vertex group
  int row = l & 15;         // m (sweep) / A-row, out col (phase C)
  int col = row + wave * 16;

  uint4 btf[16];
#pragma unroll
  for (int ks = 0; ks < 16; ++ks)
    btf[ks] = *(const uint4*)(Bt + (col * 512 + ks * 32 + q4 * 8));
  float c8[8];
#pragma unroll
  for (int m = 0; m < 8; ++m) c8[m] = var_c[m];
  float bias = var_b[col];

#define LIN_DMA(SL, TS)                                                        \
  { char* lb_ = LIN0 + (SL) * 2048;                                            \
    if ((wave & 1) == 0)                                                       \
      load16_to_lds(edge_dst + (size_t)(TS) * 256 + l * 4, lb_);               \
    else                                                                       \
      load16_to_lds(edge_vals + (size_t)(TS) * 256 + l * 4, lb_ + 1024); }
#define XUD_DMA(SL, LSL)                                                       \
  { const int* ld_ = (const int*)(LIN0 + (LSL) * 2048);                        \
    int dv_ = ld_[wave * 64 + l];                                              \
    load16_to_lds(xu_h + (size_t)dv_ * 8, XUD0 + (SL) * 4096 + wave * 1024); }
  // X' chunk permutation: dest chunk d (within v) = h + idx*2 + g*8 + cb*32
  // holds X[j = g*4+idx][cb*16 + (h? 8..15 : 0..7)]  (tr_b16-readable layout)
#define X_DMA(SL, LSL)                                                         \
  { const int* ld_ = (const int*)(LIN0 + (LSL) * 2048);                        \
    int j_ = ((l >> 3) & 3) * 4 + ((l >> 1) & 3);                              \
    int ch0_ = ((l >> 5) << 1) | (l & 1);                                      \
    _Pragma("unroll")                                                          \
    for (int s_ = 0; s_ < 8; ++s_) {                                           \
      int dv_ = ld_[wave * 64 + (s_ >> 1) * 16 + j_];                          \
      int ch_ = ch0_ + (s_ & 1) * 4;                                           \
      load16_to_lds(data_h + (size_t)dv_ * 64 + ch_ * 8,                       \
                    XB0 + (SL) * 32768 + wave * 8192 + s_ * 1024); } }

  int t0 = blockIdx.x;
  int tG1 = (t0 + GRID < NTILE) ? t0 + GRID : t0;
  int tG2 = (t0 + 2 * GRID < NTILE) ? t0 + 2 * GRID : t0;
  FENCE;
  LIN_DMA(0, t0);
  LIN_DMA(1, tG1);
  LIN_DMA(2, tG2);
  FENCE;
  uint4 xsA = *(const uint4*)(xu_h + ((size_t)t0 * 16 + wave * 4 + q4) * 8);
  uint4 xsB = *(const uint4*)(xu_h + ((size_t)tG1 * 16 + wave * 4 + q4) * 8);
  VMWAIT(0);
  __builtin_amdgcn_s_barrier();
  FENCE;
  XUD_DMA(0, 0);
  X_DMA(0, 0);
  FENCE;
  VMWAIT(0);
  __builtin_amdgcn_s_barrier();
  // prologue prepass(t0): q(t0) into XUD slot 0 (wave-private)
  PREPASS(XUD0, LIN0, xsA);
  LGKM0;

  int kc = 0;
  for (int t = t0; t < NTILE; t += GRID, ++kc) {
    int slc = kc & 1;
    int sl1 = (kc + 1) & 1, lsl1 = (kc + 1) & 3, lsl3 = (kc + 3) & 3;
    int t2c = (t + 2 * GRID < NTILE) ? t + 2 * GRID : t;
    int t3c = (t + 3 * GRID < NTILE) ? t + 3 * GRID : t;
    char* XBt = XB0 + slc * 32768;
    char* XUDt = XUD0 + slc * 4096;
    char* XUDn = XUD0 + sl1 * 4096;
    const char* LINn = LIN0 + lsl1 * 2048;

    // step1: stage next tile's xud + X' (9 DMAs; land during this iteration)
    FENCE;
    XUD_DMA(sl1, lsl1);
    X_DMA(sl1, lsl1);
    FENCE;

    // sweep(t): q(t) precomputed last iteration -> starts immediately.
    // per vertex agg[m][c] = Q[m][j] @ X[j][c] via MFMA 16x16x16.
    {
      uint2 qfr[4];
#pragma unroll
      for (int vv = 0; vv < 4; ++vv) {
        int srow = (row ^ vv) & 7;
        int gsl = (q4 ^ vv ^ row) & 3;
        qfr[vv] = *(const uint2*)(XUDt + wave * 1024 + vv * 256 + srow * 32 + gsl * 8);
      }
      unsigned xbase = lds_off(XBt + wave * 8192) + l * 8;
      uint2 trd[16];
#pragma unroll
      for (int vv = 0; vv < 4; ++vv)
#pragma unroll
        for (int cb = 0; cb < 4; ++cb) {
          unsigned a_ = xbase + vv * 2048 + cb * 512;
          asm volatile("ds_read_b64_tr_b16 %0, %1"
                       : "=v"(trd[vv * 4 + cb]) : "v"(a_) : "memory");
        }
      LGKM0;
      __builtin_amdgcn_sched_barrier(0);
      f32x4 D[16];
      __builtin_amdgcn_s_setprio(1);
#pragma unroll
      for (int vv = 0; vv < 4; ++vv)
#pragma unroll
        for (int cb = 0; cb < 4; ++cb) {
          f32x4 z = {0.f, 0.f, 0.f, 0.f};
          D[vv * 4 + cb] = __builtin_amdgcn_mfma_f32_16x16x16f16(
              __builtin_bit_cast(half4_t, trd[vv * 4 + cb]),
              __builtin_bit_cast(half4_t, qfr[vv]), z, 0, 0, 0);
        }
      __builtin_amdgcn_s_setprio(0);
      // pack + store agg (halves): lanes m = row < 8 valid
      if (row < 8) {
#pragma unroll
        for (int vv = 0; vv < 4; ++vv) {
          int vg = wave * 4 + vv;
          char* ab = XBt + vg * 2048;
#pragma unroll
          for (int cb = 0; cb < 4; ++cb) {
            f32x4 d4 = D[vv * 4 + cb];
            uint2 w2;
            w2.x = cvt_pk_u(d4[0], d4[1]);
            w2.y = cvt_pk_u(d4[2], d4[3]);
            int byte = (row * 128 + cb * 32 + q4 * 8) ^ ((vg & 7) << 4)
                       ^ ((row & 3) << 5);
            *(uint2*)(ab + byte) = w2;
          }
        }
      }
    }

    // prepass(t+1): xud(t+1) retired by VMWAIT(8) (retires y(t-1)x4 + xud;
    // X(t+1)'s 8 DMAs stay in flight). Wave-private q write into slot sl1.
    VMWAIT(8);
    PREPASS(XUDn, LINn, xsB);

    // mid: future xs reg load + lin for t+3G (after VMWAIT(8) to keep ledger)
    FENCE;
    uint4 xsC = *(const uint4*)(xu_h + ((size_t)t2c * 16 + wave * 4 + q4) * 8);
    FENCE;
    LIN_DMA(lsl3, t3c);
    FENCE;

    LGKM0;
    __builtin_amdgcn_s_barrier();   // B1: agg visible to all waves

    // phase C: 16x64 tile; wave w owns cols [16w,16w+16). Dual accumulators.
    {
      f32x4 C0 = {0.f, 0.f, 0.f, 0.f};
      f32x4 C1 = {0.f, 0.f, 0.f, 0.f};
      __builtin_amdgcn_s_setprio(1);
#pragma unroll
      for (int ks2 = 0; ks2 < 8; ++ks2) {
        int ka = 2 * ks2, kb = 2 * ks2 + 1;
        int boa = (ka * 64 + q4 * 16) ^ ((row & 7) << 4) ^ (((ka >> 1) & 3) << 5);
        int bob = (kb * 64 + q4 * 16) ^ ((row & 7) << 4) ^ (((kb >> 1) & 3) << 5);
        half8_t afa = *(const half8_t*)(XBt + row * 2048 + boa);
        half8_t afb = *(const half8_t*)(XBt + row * 2048 + bob);
        C0 = __builtin_amdgcn_mfma_f32_16x16x32_f16(
            afa, __builtin_bit_cast(half8_t, btf[ka]), C0, 0, 0, 0);
        C1 = __builtin_amdgcn_mfma_f32_16x16x32_f16(
            afb, __builtin_bit_cast(half8_t, btf[kb]), C1, 0, 0, 0);
      }
      __builtin_amdgcn_s_setprio(0);
#pragma unroll
      for (int i = 0; i < 4; ++i)
        y[(size_t)(t * 16 + q4 * 4 + i) * 64 + col] = C0[i] + C1[i] + bias;
    }
    LGKM0;       // phase-C agg reads retired before next iter's X DMA reuse
    VMWAIT(4);   // everything except the 4 y-stores retired
    __builtin_amdgcn_s_barrier();   // B2

    xsB = xsC;
    (void)xsA;
  }
  VMWAIT(0);     // drain tail (incl. dummy prefetch DMAs) before exit
#undef LIN_DMA
#undef XUD_DMA
#undef X_DMA
}

extern "C" void kernel_launch(void* const* d_in, const int* in_sizes, int n_in,
                              void* d_out, int out_size, void* d_ws, size_t ws_size,
                              hipStream_t stream) {
  const float* data      = (const float*)d_in[0];
  // d_in[1] = edge_src: structurally repeat(arange(V),16) -> implicit, unused
  const int*   edge_dst  = (const int*)d_in[2];
  const float* edge_vals = (const float*)d_in[3];
  const float* var_u     = (const float*)d_in[4];
  const float* var_c     = (const float*)d_in[5];
  const float* var_w     = (const float*)d_in[6];
  const float* var_b     = (const float*)d_in[7];
  float* y = (float*)d_out;

  char* ws = (char*)d_ws;
  unsigned short* data_h = (unsigned short*)ws;                  // 12,800,000 B
  unsigned short* xu_h   = (unsigned short*)(ws + 12800000);     //  1,600,000 B
  unsigned short* Bt     = (unsigned short*)(ws + 14400000);     //     65,536 B

  hipFuncSetAttribute((const void*)k2_main,
                      hipFuncAttributeMaxDynamicSharedMemorySize, LDSZ);

  hipLaunchKernelGGL(k1_prep, dim3((NV + 255) / 256), dim3(256), 0, stream,
                     data, var_u, var_w, data_h, xu_h, Bt);
  hipLaunchKernelGGL(k2_main, dim3(GRID), dim3(256), LDSZ, stream,
                     data_h, xu_h, edge_dst, edge_vals, Bt, var_c, var_b, y);
}